// Round 2
// baseline (330.666 us; speedup 1.0000x reference)
//
#include <hip/hip_runtime.h>

typedef unsigned short u16x8 __attribute__((ext_vector_type(8)));
typedef short          s16x8 __attribute__((ext_vector_type(8)));
typedef float          f32x4 __attribute__((ext_vector_type(4)));

#define NTOK   4096      // B*S
#define DMODEL 1024
#define NEXP   16
#define TOPK   2

// RNE float->bf16
__device__ inline unsigned short f2bf(float f) {
    unsigned int x = __float_as_uint(f);
    x += 0x7fffu + ((x >> 16) & 1u);
    return (unsigned short)(x >> 16);
}

// async global->LDS, 16B per lane. LDS dest must be wave-uniform base; HW adds lane*16.
__device__ inline void gld16(const void* g, void* l) {
    __builtin_amdgcn_global_load_lds(
        (const __attribute__((address_space(1))) void*)g,
        (__attribute__((address_space(3))) void*)l, 16, 0, 0);
}

// ---------------- routing: fp64 scores, softmax, top-2 ----------------
__global__ void routing_kernel(const float* __restrict__ u,
                               const float* __restrict__ cent,
                               const float* __restrict__ ebias,
                               float* __restrict__ topk_g,
                               int*   __restrict__ topk_i) {
    int wid  = threadIdx.x >> 6;
    int lane = threadIdx.x & 63;
    int t = blockIdx.x * 4 + wid;
    const float* urow = u + (size_t)t * DMODEL;

    double acc[NEXP];
#pragma unroll
    for (int e = 0; e < NEXP; e++) acc[e] = 0.0;

    for (int j = 0; j < DMODEL / 64; j++) {
        int d = j * 64 + lane;
        double uv = (double)urow[d];
#pragma unroll
        for (int e = 0; e < NEXP; e++)
            acc[e] += uv * (double)cent[e * DMODEL + d];
    }
#pragma unroll
    for (int e = 0; e < NEXP; e++) {
        for (int off = 32; off; off >>= 1)
            acc[e] += __shfl_xor(acc[e], off);
    }
    if (lane == 0) {
        double mx = -1e300;
#pragma unroll
        for (int e = 0; e < NEXP; e++) {
            acc[e] += (double)ebias[e];
            if (acc[e] > mx) mx = acc[e];
        }
        double ex[NEXP], den = 0.0;
#pragma unroll
        for (int e = 0; e < NEXP; e++) { ex[e] = exp(acc[e] - mx); den += ex[e]; }
        int i1 = -1, i2 = -1;
        double v1 = -1.0, v2 = -1.0;
        for (int e = 0; e < NEXP; e++) {
            double v = ex[e];
            if (v > v1)      { v2 = v1; i2 = i1; v1 = v; i1 = e; }
            else if (v > v2) { v2 = v;  i2 = e; }
        }
        topk_g[t * 2 + 0] = (float)(v1 / den);
        topk_g[t * 2 + 1] = (float)(v2 / den);
        topk_i[t * 2 + 0] = i1;
        topk_i[t * 2 + 1] = i2;
    }
}

__global__ void init_counts(int* cnt) {
    if (threadIdx.x < 64) cnt[threadIdx.x] = 0;
}

__global__ void build_lists(const float* __restrict__ topk_g,
                            const int*   __restrict__ topk_i,
                            int* __restrict__ cnt,
                            int* __restrict__ tokL,
                            float* __restrict__ gateL,
                            int* __restrict__ idL) {
    int id = blockIdx.x * 256 + threadIdx.x;   // 0..8191  (= t*2+k)
    if (id >= NTOK * TOPK) return;
    int t = id >> 1;
    int e = topk_i[id];
    float g = topk_g[id];
    int pos = atomicAdd(&cnt[e], 1);
    tokL[e * NTOK + pos]  = t;
    gateL[e * NTOK + pos] = g;
    idL[e * NTOK + pos]   = id;    // destination row in y
}

// ---------------- conversions ----------------
__global__ void conv_bf16_kernel(const float* __restrict__ src,
                                 unsigned short* __restrict__ dst, int n8) {
    int id = blockIdx.x * 256 + threadIdx.x;
    if (id >= n8) return;
    size_t base = (size_t)id * 8;
    u16x8 o;
#pragma unroll
    for (int i = 0; i < 8; i++) o[i] = f2bf(src[base + i]);
    *(u16x8*)&dst[base] = o;
}

__global__ void conv_wsum_kernel(const float* __restrict__ Ws,
                                 const float* __restrict__ bs,
                                 unsigned short* __restrict__ wsum,
                                 float* __restrict__ bsum) {
    int id = blockIdx.x * 256 + threadIdx.x;  // n8 = 131072
    if (id < 131072) {
        size_t base = (size_t)id * 8;
        u16x8 o;
#pragma unroll
        for (int i = 0; i < 8; i++)
            o[i] = f2bf(Ws[base + i] + Ws[(size_t)DMODEL * DMODEL + base + i]);
        *(u16x8*)&wsum[base] = o;
    }
    if (id < DMODEL) bsum[id] = bs[id] + bs[DMODEL + id];
}

// ---------------- GEMMs: m97 structure. BM=BN=128, BK=64, 4 waves, 4x4 frags ----------------
// Linear LDS [128][64] bf16 (global_load_lds requires contiguous dest).

__global__ __launch_bounds__(256)
void shared_gemm(const unsigned short* __restrict__ ub,    // [4096][1024] bf16
                 const unsigned short* __restrict__ wsum,  // [1024][1024] bf16 (B^T layout)
                 const float* __restrict__ bsum,
                 const float* __restrict__ u,
                 float* __restrict__ out) {
    __shared__ __align__(16) unsigned short As[128 * 64];
    __shared__ __align__(16) unsigned short Bs[128 * 64];

    int t = threadIdx.x;
    int lane = t & 63, wid = t >> 6;
    int m0 = blockIdx.x * 128, n0 = blockIdx.y * 128;
    int wm = wid >> 1, wn = wid & 1;
    int lr = lane & 15, lk = (lane >> 4) * 8;
    int srow_in = lane >> 3;           // 0..7 within 8-row pass
    int scol = (lane & 7) * 8;

    f32x4 acc[4][4];
#pragma unroll
    for (int i = 0; i < 4; i++)
#pragma unroll
        for (int j = 0; j < 4; j++)
#pragma unroll
            for (int v = 0; v < 4; v++) acc[i][j][v] = 0.0f;

    for (int k0 = 0; k0 < DMODEL; k0 += 64) {
#pragma unroll
        for (int p = 0; p < 4; p++) {
            int r = wid * 32 + p * 8;                 // wave-uniform row group
            int rr = r + srow_in;
            gld16(&ub[(size_t)(m0 + rr) * DMODEL + k0 + scol], &As[r * 64]);
            gld16(&wsum[(size_t)(n0 + rr) * DMODEL + k0 + scol], &Bs[r * 64]);
        }
        __syncthreads();
#pragma unroll
        for (int ks = 0; ks < 2; ks++) {
            int kk = ks * 32 + lk;
            s16x8 a[4], b[4];
#pragma unroll
            for (int i = 0; i < 4; i++)
                a[i] = *(const s16x8*)&As[(wm * 64 + i * 16 + lr) * 64 + kk];
#pragma unroll
            for (int j = 0; j < 4; j++)
                b[j] = *(const s16x8*)&Bs[(wn * 64 + j * 16 + lr) * 64 + kk];
#pragma unroll
            for (int i = 0; i < 4; i++)
#pragma unroll
                for (int j = 0; j < 4; j++)
                    acc[i][j] = __builtin_amdgcn_mfma_f32_16x16x32_bf16(
                        a[i], b[j], acc[i][j], 0, 0, 0);
        }
        __syncthreads();
    }

    int rbase = m0 + wm * 64 + (lane >> 4) * 4;
    int cbase = n0 + wn * 64 + lr;
#pragma unroll
    for (int i = 0; i < 4; i++) {
#pragma unroll
        for (int j = 0; j < 4; j++) {
            int col = cbase + j * 16;
            float bv = bsum[col];
#pragma unroll
            for (int v = 0; v < 4; v++) {
                int row = rbase + i * 16 + v;
                size_t idx = (size_t)row * DMODEL + col;
                out[idx] = u[idx] + 0.5f * (acc[i][j][v] + bv);
            }
        }
    }
}

__global__ __launch_bounds__(256)
void routed_gemm(const unsigned short* __restrict__ ub,   // [4096][1024] bf16
                 const unsigned short* __restrict__ wr,   // [16][1024][1024] bf16
                 const float* __restrict__ br,            // [16][1024]
                 const int*   __restrict__ cnt,
                 const int*   __restrict__ tokL,
                 const float* __restrict__ gateL,
                 const int*   __restrict__ idL,
                 float* __restrict__ y) {                 // [8192][1024] f32
    int e  = blockIdx.x >> 5;       // 32 m-tiles of 128
    int mt = blockIdx.x & 31;
    int count = cnt[e];
    if (mt * 128 >= count) return;

    __shared__ __align__(16) unsigned short As[128 * 64];
    __shared__ __align__(16) unsigned short Bs[128 * 64];

    int t = threadIdx.x;
    int lane = t & 63, wid = t >> 6;
    int n0 = blockIdx.y * 128;
    int wm = wid >> 1, wn = wid & 1;
    int lr = lane & 15, lk = (lane >> 4) * 8;
    int srow_in = lane >> 3;
    int scol = (lane & 7) * 8;

    const int* tl = tokL + e * NTOK;
    int tokp[4];
#pragma unroll
    for (int p = 0; p < 4; p++) {
        int gi = mt * 128 + wid * 32 + p * 8 + srow_in;
        tokp[p] = tl[gi < count ? gi : count - 1];
    }
    const unsigned short* we = wr + (size_t)e * DMODEL * DMODEL;

    f32x4 acc[4][4];
#pragma unroll
    for (int i = 0; i < 4; i++)
#pragma unroll
        for (int j = 0; j < 4; j++)
#pragma unroll
            for (int v = 0; v < 4; v++) acc[i][j][v] = 0.0f;

    for (int k0 = 0; k0 < DMODEL; k0 += 64) {
#pragma unroll
        for (int p = 0; p < 4; p++) {
            int r = wid * 32 + p * 8;
            int rr = r + srow_in;
            gld16(&ub[(size_t)tokp[p] * DMODEL + k0 + scol], &As[r * 64]);
            gld16(&we[(size_t)(n0 + rr) * DMODEL + k0 + scol], &Bs[r * 64]);
        }
        __syncthreads();
#pragma unroll
        for (int ks = 0; ks < 2; ks++) {
            int kk = ks * 32 + lk;
            s16x8 a[4], b[4];
#pragma unroll
            for (int i = 0; i < 4; i++)
                a[i] = *(const s16x8*)&As[(wm * 64 + i * 16 + lr) * 64 + kk];
#pragma unroll
            for (int j = 0; j < 4; j++)
                b[j] = *(const s16x8*)&Bs[(wn * 64 + j * 16 + lr) * 64 + kk];
#pragma unroll
            for (int i = 0; i < 4; i++)
#pragma unroll
                for (int j = 0; j < 4; j++)
                    acc[i][j] = __builtin_amdgcn_mfma_f32_16x16x32_bf16(
                        a[i], b[j], acc[i][j], 0, 0, 0);
        }
        __syncthreads();
    }

    int cb = n0 + wn * 64 + lr;
#pragma unroll
    for (int i = 0; i < 4; i++) {
#pragma unroll
        for (int v = 0; v < 4; v++) {
            int gi = mt * 128 + wm * 64 + i * 16 + (lane >> 4) * 4 + v;
            if (gi < count) {
                int id = idL[e * NTOK + gi];
                float g = gateL[e * NTOK + gi];
                float* yr = y + (size_t)id * DMODEL;
#pragma unroll
                for (int j = 0; j < 4; j++) {
                    int col = cb + j * 16;
                    yr[col] = g * (acc[i][j][v] + br[e * DMODEL + col]);
                }
            }
        }
    }
}

// out[t] += y[2t] + y[2t+1]
__global__ void combine_kernel(const float* __restrict__ y, float* __restrict__ out) {
    int idx = blockIdx.x * 256 + threadIdx.x;   // 1M threads, 4 floats each
    size_t base = (size_t)idx * 4;
    int tk = idx >> 8;                          // token = idx / (1024/4)
    int d4 = idx & 255;
    f32x4 o  = *(const f32x4*)&out[base];
    f32x4 y0 = *(const f32x4*)&y[(size_t)(tk * 2) * DMODEL + d4 * 4];
    f32x4 y1 = *(const f32x4*)&y[(size_t)(tk * 2 + 1) * DMODEL + d4 * 4];
#pragma unroll
    for (int v = 0; v < 4; v++) o[v] += y0[v] + y1[v];
    *(f32x4*)&out[base] = o;
}

extern "C" void kernel_launch(void* const* d_in, const int* in_sizes, int n_in,
                              void* d_out, int out_size, void* d_ws, size_t ws_size,
                              hipStream_t stream) {
    const float* u    = (const float*)d_in[0];
    const float* cent = (const float*)d_in[1];
    const float* eb   = (const float*)d_in[2];
    const float* Wr   = (const float*)d_in[3];
    const float* br   = (const float*)d_in[4];
    const float* Ws   = (const float*)d_in[5];
    const float* bs   = (const float*)d_in[6];
    float* out = (float*)d_out;

    char* ws = (char*)d_ws;
    size_t off = 0;
    auto take = [&](size_t b) { size_t o = off; off += (b + 255) & ~(size_t)255; return o; };
    float* topk_g = (float*)(ws + take(NTOK * TOPK * 4));
    int*   topk_i = (int*)  (ws + take(NTOK * TOPK * 4));
    int*   cnt    = (int*)  (ws + take(64 * 4));
    int*   tokL   = (int*)  (ws + take((size_t)NEXP * NTOK * 4));
    float* gateL  = (float*)(ws + take((size_t)NEXP * NTOK * 4));
    int*   idL    = (int*)  (ws + take((size_t)NEXP * NTOK * 4));
    float* bsum   = (float*)(ws + take(DMODEL * 4));
    unsigned short* ub   = (unsigned short*)(ws + take((size_t)NTOK * DMODEL * 2));
    unsigned short* wsum = (unsigned short*)(ws + take((size_t)DMODEL * DMODEL * 2));
    unsigned short* wr16 = (unsigned short*)(ws + take((size_t)NEXP * DMODEL * DMODEL * 2));
    float* y = (float*)(ws + take((size_t)NTOK * TOPK * DMODEL * 4));

    routing_kernel<<<NTOK / 4, 256, 0, stream>>>(u, cent, eb, topk_g, topk_i);
    init_counts<<<1, 64, 0, stream>>>(cnt);
    build_lists<<<(NTOK * TOPK + 255) / 256, 256, 0, stream>>>(topk_g, topk_i, cnt, tokL, gateL, idL);
    conv_bf16_kernel<<<(NTOK * DMODEL / 8 + 255) / 256, 256, 0, stream>>>(u, ub, NTOK * DMODEL / 8);
    conv_bf16_kernel<<<(NEXP * DMODEL * DMODEL / 8 + 255) / 256, 256, 0, stream>>>(
        Wr, wr16, NEXP * DMODEL * DMODEL / 8);
    conv_wsum_kernel<<<(DMODEL * DMODEL / 8 + 255) / 256, 256, 0, stream>>>(Ws, bs, wsum, bsum);
    shared_gemm<<<dim3(NTOK / 128, DMODEL / 128), 256, 0, stream>>>(ub, wsum, bsum, u, out);
    routed_gemm<<<dim3(NEXP * (NTOK / 128), DMODEL / 128), 256, 0, stream>>>(
        ub, wr16, br, cnt, tokL, gateL, idL, y);
    combine_kernel<<<(NTOK * DMODEL / 4) / 256, 256, 0, stream>>>(y, out);
}

// Round 3
// 162.745 us; speedup vs baseline: 2.0318x; 2.0318x over previous
//
#include <hip/hip_runtime.h>

typedef unsigned short u16x8 __attribute__((ext_vector_type(8)));
typedef short          s16x8 __attribute__((ext_vector_type(8)));
typedef float          f32x4 __attribute__((ext_vector_type(4)));

#define NTOK   4096      // B*S
#define DMODEL 1024
#define NEXP   16
#define TOPK   2
#define MAXT   144       // max total BM=64 m-tiles across experts (<=143)

// RNE float->bf16
__device__ inline unsigned short f2bf(float f) {
    unsigned int x = __float_as_uint(f);
    x += 0x7fffu + ((x >> 16) & 1u);
    return (unsigned short)(x >> 16);
}

// async global->LDS, 16B/lane; LDS dest wave-uniform base, HW adds lane*16
__device__ inline void gld16(const void* g, void* l) {
    __builtin_amdgcn_global_load_lds(
        (const __attribute__((address_space(1))) void*)g,
        (__attribute__((address_space(3))) void*)l, 16, 0, 0);
}

// ---------------- routing: fp64 scores, softmax, top-2 ----------------
__global__ void routing_kernel(const float* __restrict__ u,
                               const float* __restrict__ cent,
                               const float* __restrict__ ebias,
                               float* __restrict__ topk_g,
                               int*   __restrict__ topk_i) {
    int wid  = threadIdx.x >> 6;
    int lane = threadIdx.x & 63;
    int t = blockIdx.x * 4 + wid;
    const float* urow = u + (size_t)t * DMODEL;

    double acc[NEXP];
#pragma unroll
    for (int e = 0; e < NEXP; e++) acc[e] = 0.0;

    for (int j = 0; j < DMODEL / 64; j++) {
        int d = j * 64 + lane;
        double uv = (double)urow[d];
#pragma unroll
        for (int e = 0; e < NEXP; e++)
            acc[e] += uv * (double)cent[e * DMODEL + d];
    }
#pragma unroll
    for (int e = 0; e < NEXP; e++) {
        for (int off = 32; off; off >>= 1)
            acc[e] += __shfl_xor(acc[e], off);
    }
    if (lane == 0) {
        double mx = -1e300;
#pragma unroll
        for (int e = 0; e < NEXP; e++) {
            acc[e] += (double)ebias[e];
            if (acc[e] > mx) mx = acc[e];
        }
        double ex[NEXP], den = 0.0;
#pragma unroll
        for (int e = 0; e < NEXP; e++) { ex[e] = exp(acc[e] - mx); den += ex[e]; }
        int i1 = -1, i2 = -1;
        double v1 = -1.0, v2 = -1.0;
        for (int e = 0; e < NEXP; e++) {
            double v = ex[e];
            if (v > v1)      { v2 = v1; i2 = i1; v1 = v; i1 = e; }
            else if (v > v2) { v2 = v;  i2 = e; }
        }
        topk_g[t * 2 + 0] = (float)(v1 / den);
        topk_g[t * 2 + 1] = (float)(v2 / den);
        topk_i[t * 2 + 0] = i1;
        topk_i[t * 2 + 1] = i2;
    }
}

__global__ void init_counts(int* cnt) {
    if (threadIdx.x < 64) cnt[threadIdx.x] = 0;
}

__global__ void build_lists(const float* __restrict__ topk_g,
                            const int*   __restrict__ topk_i,
                            int* __restrict__ cnt,
                            int* __restrict__ tokL,
                            float* __restrict__ gateL,
                            int* __restrict__ idL) {
    int id = blockIdx.x * 256 + threadIdx.x;   // 0..8191  (= t*2+k)
    if (id >= NTOK * TOPK) return;
    int t = id >> 1;
    int e = topk_i[id];
    float g = topk_g[id];
    int pos = atomicAdd(&cnt[e], 1);
    tokL[e * NTOK + pos]  = t;
    gateL[e * NTOK + pos] = g;
    idL[e * NTOK + pos]   = id;    // destination row in y
}

// tile descriptors: one entry per (expert, m-tile of 64 rows)
__global__ void build_desc(const int* __restrict__ cnt,
                           int* __restrict__ desc,
                           int* __restrict__ numTiles) {
    __shared__ int base[NEXP + 1];
    if (threadIdx.x == 0) {
        int s = 0;
        for (int e = 0; e < NEXP; e++) {
            base[e] = s;
            s += (cnt[e] + 63) >> 6;
        }
        base[NEXP] = s;
        numTiles[0] = s;
    }
    __syncthreads();
    for (int e = 0; e < NEXP; e++) {
        int nt = base[e + 1] - base[e];
        if ((int)threadIdx.x < nt)
            desc[base[e] + threadIdx.x] = (e << 16) | threadIdx.x;
    }
}

// ---------------- conversions ----------------
__global__ void conv_bf16_kernel(const float* __restrict__ src,
                                 unsigned short* __restrict__ dst, int n8) {
    int id = blockIdx.x * 256 + threadIdx.x;
    if (id >= n8) return;
    size_t base = (size_t)id * 8;
    u16x8 o;
#pragma unroll
    for (int i = 0; i < 8; i++) o[i] = f2bf(src[base + i]);
    *(u16x8*)&dst[base] = o;
}

__global__ void conv_wsum_kernel(const float* __restrict__ Ws,
                                 const float* __restrict__ bs,
                                 unsigned short* __restrict__ wsum,
                                 float* __restrict__ bsum) {
    int id = blockIdx.x * 256 + threadIdx.x;  // n8 = 131072
    if (id < 131072) {
        size_t base = (size_t)id * 8;
        u16x8 o;
#pragma unroll
        for (int i = 0; i < 8; i++)
            o[i] = f2bf(Ws[base + i] + Ws[(size_t)DMODEL * DMODEL + base + i]);
        *(u16x8*)&wsum[base] = o;
    }
    if (id < DMODEL) bsum[id] = bs[id] + bs[DMODEL + id];
}

// ============ GEMMs: BM=64, BN=128, BK=64, 4 waves, 2-phase dbuf ============
// Each wave computes full 64 rows x 32 cols (a[4] x b[2] frags, 16 MFMA/K-step).
// LDS linear (global_load_lds needs contiguous dest); dbuf 48KB -> 3 blocks/CU.

__global__ __launch_bounds__(256)
void shared_gemm(const unsigned short* __restrict__ ub,    // [4096][1024] bf16
                 const unsigned short* __restrict__ wsum,  // [1024][1024] bf16 (B^T)
                 const float* __restrict__ bsum,
                 const float* __restrict__ u,
                 float* __restrict__ out) {
    __shared__ __align__(16) unsigned short As[2][64 * 64];
    __shared__ __align__(16) unsigned short Bs[2][128 * 64];

    int t = threadIdx.x;
    int lane = t & 63, wid = t >> 6;
    int m0 = blockIdx.x * 64, n0 = blockIdx.y * 128;
    int lr = lane & 15, lk4 = lane >> 4;           // lk4: 0..3
    int srow = lane >> 3, scol = (lane & 7) * 8;

    const unsigned short* abase = ub + (size_t)m0 * DMODEL;
    const unsigned short* bbase = wsum + (size_t)n0 * DMODEL;

#define STAGE_S(buf, k0) do {                                                   \
    _Pragma("unroll")                                                           \
    for (int p = 0; p < 2; p++) {                                               \
        int r = wid * 16 + p * 8;                                               \
        gld16(&abase[(size_t)(r + srow) * DMODEL + (k0) + scol], &As[buf][r * 64]); \
    }                                                                           \
    _Pragma("unroll")                                                           \
    for (int p = 0; p < 4; p++) {                                               \
        int r = wid * 32 + p * 8;                                               \
        gld16(&bbase[(size_t)(r + srow) * DMODEL + (k0) + scol], &Bs[buf][r * 64]); \
    } } while (0)

    f32x4 acc[4][2];
#pragma unroll
    for (int i = 0; i < 4; i++)
#pragma unroll
        for (int j = 0; j < 2; j++)
#pragma unroll
            for (int v = 0; v < 4; v++) acc[i][j][v] = 0.0f;

    STAGE_S(0, 0);
    __syncthreads();
    int cur = 0;
    for (int kt = 0; kt < DMODEL / 64; kt++) {
        if (kt != DMODEL / 64 - 1) STAGE_S(cur ^ 1, (kt + 1) * 64);
#pragma unroll
        for (int ks = 0; ks < 2; ks++) {
            int kk = ks * 32 + lk4 * 8;
            s16x8 a[4], b[2];
#pragma unroll
            for (int i = 0; i < 4; i++)
                a[i] = *(const s16x8*)&As[cur][(i * 16 + lr) * 64 + kk];
#pragma unroll
            for (int j = 0; j < 2; j++)
                b[j] = *(const s16x8*)&Bs[cur][(wid * 32 + j * 16 + lr) * 64 + kk];
#pragma unroll
            for (int i = 0; i < 4; i++)
#pragma unroll
                for (int j = 0; j < 2; j++)
                    acc[i][j] = __builtin_amdgcn_mfma_f32_16x16x32_bf16(
                        a[i], b[j], acc[i][j], 0, 0, 0);
        }
        __syncthreads();
        cur ^= 1;
    }
#undef STAGE_S

    int rbase = m0 + lk4 * 4;
    int cbase = n0 + wid * 32 + lr;
#pragma unroll
    for (int i = 0; i < 4; i++) {
#pragma unroll
        for (int j = 0; j < 2; j++) {
            int col = cbase + j * 16;
            float bv = bsum[col];
#pragma unroll
            for (int v = 0; v < 4; v++) {
                int row = rbase + i * 16 + v;
                size_t idx = (size_t)row * DMODEL + col;
                out[idx] = u[idx] + 0.5f * (acc[i][j][v] + bv);
            }
        }
    }
}

__global__ __launch_bounds__(256)
void routed_gemm(const unsigned short* __restrict__ ub,   // [4096][1024] bf16
                 const unsigned short* __restrict__ wr,   // [16][1024][1024] bf16
                 const float* __restrict__ br,            // [16][1024]
                 const int*   __restrict__ cnt,
                 const int*   __restrict__ tokL,
                 const float* __restrict__ gateL,
                 const int*   __restrict__ idL,
                 const int*   __restrict__ desc,
                 const int*   __restrict__ numTiles,
                 float* __restrict__ y) {                 // [8192][1024] f32
    if ((int)blockIdx.y >= numTiles[0]) return;
    int d = desc[blockIdx.y];
    int e = d >> 16;
    int row0 = (d & 0xffff) << 6;
    int count = cnt[e];

    __shared__ __align__(16) unsigned short As[2][64 * 64];
    __shared__ __align__(16) unsigned short Bs[2][128 * 64];

    int t = threadIdx.x;
    int lane = t & 63, wid = t >> 6;
    int n0 = blockIdx.x * 128;
    int lr = lane & 15, lk4 = lane >> 4;
    int srow = lane >> 3, scol = (lane & 7) * 8;

    const int* tl = tokL + e * NTOK;
    int tok_a[2];
#pragma unroll
    for (int p = 0; p < 2; p++) {
        int gi = row0 + wid * 16 + p * 8 + srow;
        tok_a[p] = tl[gi < count ? gi : count - 1];
    }
    const unsigned short* bbase = wr + (size_t)e * DMODEL * DMODEL + (size_t)n0 * DMODEL;

#define STAGE_R(buf, k0) do {                                                   \
    _Pragma("unroll")                                                           \
    for (int p = 0; p < 2; p++) {                                               \
        int r = wid * 16 + p * 8;                                               \
        gld16(&ub[(size_t)tok_a[p] * DMODEL + (k0) + scol], &As[buf][r * 64]);  \
    }                                                                           \
    _Pragma("unroll")                                                           \
    for (int p = 0; p < 4; p++) {                                               \
        int r = wid * 32 + p * 8;                                               \
        gld16(&bbase[(size_t)(r + srow) * DMODEL + (k0) + scol], &Bs[buf][r * 64]); \
    } } while (0)

    f32x4 acc[4][2];
#pragma unroll
    for (int i = 0; i < 4; i++)
#pragma unroll
        for (int j = 0; j < 2; j++)
#pragma unroll
            for (int v = 0; v < 4; v++) acc[i][j][v] = 0.0f;

    STAGE_R(0, 0);
    __syncthreads();
    int cur = 0;
    for (int kt = 0; kt < DMODEL / 64; kt++) {
        if (kt != DMODEL / 64 - 1) STAGE_R(cur ^ 1, (kt + 1) * 64);
#pragma unroll
        for (int ks = 0; ks < 2; ks++) {
            int kk = ks * 32 + lk4 * 8;
            s16x8 a[4], b[2];
#pragma unroll
            for (int i = 0; i < 4; i++)
                a[i] = *(const s16x8*)&As[cur][(i * 16 + lr) * 64 + kk];
#pragma unroll
            for (int j = 0; j < 2; j++)
                b[j] = *(const s16x8*)&Bs[cur][(wid * 32 + j * 16 + lr) * 64 + kk];
#pragma unroll
            for (int i = 0; i < 4; i++)
#pragma unroll
                for (int j = 0; j < 2; j++)
                    acc[i][j] = __builtin_amdgcn_mfma_f32_16x16x32_bf16(
                        a[i], b[j], acc[i][j], 0, 0, 0);
        }
        __syncthreads();
        cur ^= 1;
    }
#undef STAGE_R

    int cbase = n0 + wid * 32 + lr;
#pragma unroll
    for (int i = 0; i < 4; i++) {
#pragma unroll
        for (int v = 0; v < 4; v++) {
            int gi = row0 + i * 16 + lk4 * 4 + v;
            if (gi < count) {
                int id = idL[e * NTOK + gi];
                float g = gateL[e * NTOK + gi];
                float* yr = y + (size_t)id * DMODEL;
#pragma unroll
                for (int j = 0; j < 2; j++) {
                    int col = cbase + j * 16;
                    yr[col] = g * (acc[i][j][v] + br[e * DMODEL + col]);
                }
            }
        }
    }
}

// out[t] += y[2t] + y[2t+1]
__global__ void combine_kernel(const float* __restrict__ y, float* __restrict__ out) {
    int idx = blockIdx.x * 256 + threadIdx.x;
    size_t base = (size_t)idx * 4;
    int tk = idx >> 8;
    int d4 = idx & 255;
    f32x4 o  = *(const f32x4*)&out[base];
    f32x4 y0 = *(const f32x4*)&y[(size_t)(tk * 2) * DMODEL + d4 * 4];
    f32x4 y1 = *(const f32x4*)&y[(size_t)(tk * 2 + 1) * DMODEL + d4 * 4];
#pragma unroll
    for (int v = 0; v < 4; v++) o[v] += y0[v] + y1[v];
    *(f32x4*)&out[base] = o;
}

extern "C" void kernel_launch(void* const* d_in, const int* in_sizes, int n_in,
                              void* d_out, int out_size, void* d_ws, size_t ws_size,
                              hipStream_t stream) {
    const float* u    = (const float*)d_in[0];
    const float* cent = (const float*)d_in[1];
    const float* eb   = (const float*)d_in[2];
    const float* Wr   = (const float*)d_in[3];
    const float* br   = (const float*)d_in[4];
    const float* Ws   = (const float*)d_in[5];
    const float* bs   = (const float*)d_in[6];
    float* out = (float*)d_out;

    char* ws = (char*)d_ws;
    size_t off = 0;
    auto take = [&](size_t b) { size_t o = off; off += (b + 255) & ~(size_t)255; return o; };
    float* topk_g = (float*)(ws + take(NTOK * TOPK * 4));
    int*   topk_i = (int*)  (ws + take(NTOK * TOPK * 4));
    int*   cnt    = (int*)  (ws + take(64 * 4));
    int*   tokL   = (int*)  (ws + take((size_t)NEXP * NTOK * 4));
    float* gateL  = (float*)(ws + take((size_t)NEXP * NTOK * 4));
    int*   idL    = (int*)  (ws + take((size_t)NEXP * NTOK * 4));
    int*   desc   = (int*)  (ws + take(MAXT * 4));
    int*   numT   = (int*)  (ws + take(64));
    float* bsum   = (float*)(ws + take(DMODEL * 4));
    unsigned short* ub   = (unsigned short*)(ws + take((size_t)NTOK * DMODEL * 2));
    unsigned short* wsum = (unsigned short*)(ws + take((size_t)DMODEL * DMODEL * 2));
    unsigned short* wr16 = (unsigned short*)(ws + take((size_t)NEXP * DMODEL * DMODEL * 2));
    float* y = (float*)(ws + take((size_t)NTOK * TOPK * DMODEL * 4));

    routing_kernel<<<NTOK / 4, 256, 0, stream>>>(u, cent, eb, topk_g, topk_i);
    init_counts<<<1, 64, 0, stream>>>(cnt);
    build_lists<<<(NTOK * TOPK + 255) / 256, 256, 0, stream>>>(topk_g, topk_i, cnt, tokL, gateL, idL);
    build_desc<<<1, 256, 0, stream>>>(cnt, desc, numT);
    conv_bf16_kernel<<<(NTOK * DMODEL / 8 + 255) / 256, 256, 0, stream>>>(u, ub, NTOK * DMODEL / 8);
    conv_bf16_kernel<<<(NEXP * DMODEL * DMODEL / 8 + 255) / 256, 256, 0, stream>>>(
        Wr, wr16, NEXP * DMODEL * DMODEL / 8);
    conv_wsum_kernel<<<(DMODEL * DMODEL / 8 + 255) / 256, 256, 0, stream>>>(Ws, bs, wsum, bsum);
    shared_gemm<<<dim3(NTOK / 64, DMODEL / 128), 256, 0, stream>>>(ub, wsum, bsum, u, out);
    routed_gemm<<<dim3(DMODEL / 128, MAXT), 256, 0, stream>>>(
        ub, wr16, br, cnt, tokL, gateL, idL, desc, numT, y);
    combine_kernel<<<(NTOK * DMODEL / 4) / 256, 256, 0, stream>>>(y, out);
}

// Round 4
// 129.674 us; speedup vs baseline: 2.5500x; 1.2550x over previous
//
#include <hip/hip_runtime.h>

typedef unsigned short u16x8 __attribute__((ext_vector_type(8)));
typedef short          s16x8 __attribute__((ext_vector_type(8)));
typedef float          f32x4 __attribute__((ext_vector_type(4)));

#define NTOK   4096      // B*S
#define DMODEL 1024
#define NEXP   16
#define TOPK   2
#define MAXT   128       // desc capacity: 32 shared tiles + <=80 routed tiles

// RNE float->bf16
__device__ inline unsigned short f2bf(float f) {
    unsigned int x = __float_as_uint(f);
    x += 0x7fffu + ((x >> 16) & 1u);
    return (unsigned short)(x >> 16);
}

// async global->LDS, 16B/lane; LDS dest wave-uniform base, HW adds lane*16
__device__ inline void gld16(const void* g, void* l) {
    __builtin_amdgcn_global_load_lds(
        (const __attribute__((address_space(1))) void*)g,
        (__attribute__((address_space(3))) void*)l, 16, 0, 0);
}

// ------------- routing: fp64 scores, softmax, top-2; fused u->bf16 -------------
__global__ void routing_kernel(const float* __restrict__ u,
                               const float* __restrict__ cent,
                               const float* __restrict__ ebias,
                               float* __restrict__ topk_g,
                               int*   __restrict__ topk_i,
                               unsigned short* __restrict__ ub) {
    int wid  = threadIdx.x >> 6;
    int lane = threadIdx.x & 63;
    int t = blockIdx.x * 4 + wid;
    const float* urow = u + (size_t)t * DMODEL;

    double acc[NEXP];
#pragma unroll
    for (int e = 0; e < NEXP; e++) acc[e] = 0.0;

    for (int j = 0; j < DMODEL / 64; j++) {
        int d = j * 64 + lane;
        float uf = urow[d];
        ub[(size_t)t * DMODEL + d] = f2bf(uf);
        double uv = (double)uf;
#pragma unroll
        for (int e = 0; e < NEXP; e++)
            acc[e] += uv * (double)cent[e * DMODEL + d];
    }
#pragma unroll
    for (int e = 0; e < NEXP; e++) {
        for (int off = 32; off; off >>= 1)
            acc[e] += __shfl_xor(acc[e], off);
    }
    if (lane == 0) {
        double mx = -1e300;
#pragma unroll
        for (int e = 0; e < NEXP; e++) {
            acc[e] += (double)ebias[e];
            if (acc[e] > mx) mx = acc[e];
        }
        double ex[NEXP], den = 0.0;
#pragma unroll
        for (int e = 0; e < NEXP; e++) { ex[e] = exp(acc[e] - mx); den += ex[e]; }
        int i1 = -1, i2 = -1;
        double v1 = -1.0, v2 = -1.0;
        for (int e = 0; e < NEXP; e++) {
            double v = ex[e];
            if (v > v1)      { v2 = v1; i2 = i1; v1 = v; i1 = e; }
            else if (v > v2) { v2 = v;  i2 = e; }
        }
        topk_g[t * 2 + 0] = (float)(v1 / den);
        topk_g[t * 2 + 1] = (float)(v2 / den);
        topk_i[t * 2 + 0] = i1;
        topk_i[t * 2 + 1] = i2;
    }
}

// ------------- single-block: bucket token-expert pairs + tile descriptors -------------
__global__ void build_all(const float* __restrict__ topk_g,
                          const int*   __restrict__ topk_i,
                          int* __restrict__ cnt,
                          int* __restrict__ tokL,
                          float* __restrict__ gateL,
                          int* __restrict__ idL,
                          int* __restrict__ desc,
                          int* __restrict__ numT) {
    __shared__ int scnt[NEXP];
    int tid = threadIdx.x;
    if (tid < NEXP) scnt[tid] = 0;
    __syncthreads();
    for (int id = tid; id < NTOK * TOPK; id += 1024) {
        int e = topk_i[id];
        int pos = atomicAdd(&scnt[e], 1);
        tokL[e * NTOK + pos]  = id >> 1;
        gateL[e * NTOK + pos] = topk_g[id];
        idL[e * NTOK + pos]   = id;
    }
    __syncthreads();
    if (tid == 0) {
        int s = 0;
        for (int mt = 0; mt < NTOK / 128; mt++) desc[s++] = (NEXP << 16) | mt; // shared
        for (int e = 0; e < NEXP; e++) {
            cnt[e] = scnt[e];
            int nt = (scnt[e] + 127) >> 7;
            for (int m = 0; m < nt; m++) desc[s++] = (e << 16) | m;
        }
        numT[0] = s;
    }
}

// ------------- all weight/bias conversions in one kernel -------------
// w17: [17][1024][1024] bf16  (experts 0..15 = Wr, 16 = Ws0+Ws1)
// b17: [17][1024] f32         (0..15 = br, 16 = bs0+bs1)
#define NWR8  (NEXP * DMODEL * DMODEL / 8)       // 2097152
#define NWS8  (DMODEL * DMODEL / 8)              // 131072
#define NB8   ((NEXP + 1) * DMODEL / 8)          // 2176
__global__ void conv_w(const float* __restrict__ Wr,
                       const float* __restrict__ br,
                       const float* __restrict__ Ws,
                       const float* __restrict__ bs,
                       unsigned short* __restrict__ w17,
                       float* __restrict__ b17) {
    int id = blockIdx.x * 256 + threadIdx.x;
    if (id < NWR8) {
        size_t base = (size_t)id * 8;
        u16x8 o;
#pragma unroll
        for (int i = 0; i < 8; i++) o[i] = f2bf(Wr[base + i]);
        *(u16x8*)&w17[base] = o;
    } else if (id < NWR8 + NWS8) {
        size_t base = (size_t)(id - NWR8) * 8;
        u16x8 o;
#pragma unroll
        for (int i = 0; i < 8; i++)
            o[i] = f2bf(Ws[base + i] + Ws[(size_t)DMODEL * DMODEL + base + i]);
        *(u16x8*)&w17[(size_t)NEXP * DMODEL * DMODEL + base] = o;
    } else if (id < NWR8 + NWS8 + NB8) {
        int base = (id - NWR8 - NWS8) * 8;
#pragma unroll
        for (int i = 0; i < 8; i++) {
            int idx = base + i;
            b17[idx] = idx < NEXP * DMODEL ? br[idx]
                                           : bs[idx - NEXP * DMODEL] + bs[idx - NEXP * DMODEL + DMODEL];
        }
    }
}

// ============ merged MoE GEMM: m97 structure ============
// BM=BN=128, BK=64, 4 waves (2x2), 4x4 frags, single 32KB LDS buffer,
// global_load_lds 16B staging, 2 barriers per K-step.
__global__ __launch_bounds__(256)
void moe_gemm(const unsigned short* __restrict__ ub,   // [4096][1024] bf16
              const unsigned short* __restrict__ w17,  // [17][1024][1024] bf16 (B^T)
              const float* __restrict__ b17,           // [17][1024]
              const int*   __restrict__ cnt,
              const int*   __restrict__ tokL,
              const float* __restrict__ gateL,
              const int*   __restrict__ idL,
              const int*   __restrict__ desc,
              const int*   __restrict__ numT,
              const float* __restrict__ u,
              float* __restrict__ out,
              float* __restrict__ y) {                 // [8192][1024] f32
    if ((int)blockIdx.y >= numT[0]) return;
    int d = desc[blockIdx.y];
    int e = d >> 16;
    int row0 = (d & 0xffff) << 7;
    bool is_shared = (e == NEXP);
    int count = is_shared ? NTOK : cnt[e];

    __shared__ __align__(16) unsigned short As[128 * 64];
    __shared__ __align__(16) unsigned short Bs[128 * 64];

    int t = threadIdx.x;
    int lane = t & 63, wid = t >> 6;
    int n0 = blockIdx.x * 128;
    int wm = wid >> 1, wn = wid & 1;
    int lr = lane & 15, lk4 = lane >> 4;
    int srow = lane >> 3, scol = (lane & 7) * 8;

    const int* tl = tokL + e * NTOK;
    int tok_a[4];
#pragma unroll
    for (int p = 0; p < 4; p++) {
        int gi = row0 + wid * 32 + p * 8 + srow;
        tok_a[p] = is_shared ? gi : tl[gi < count ? gi : count - 1];
    }
    const unsigned short* bbase =
        w17 + (size_t)e * DMODEL * DMODEL + (size_t)n0 * DMODEL;

    f32x4 acc[4][4];
#pragma unroll
    for (int i = 0; i < 4; i++)
#pragma unroll
        for (int j = 0; j < 4; j++)
#pragma unroll
            for (int v = 0; v < 4; v++) acc[i][j][v] = 0.0f;

    for (int kt = 0; kt < DMODEL / 64; kt++) {
        int k0 = kt * 64;
#pragma unroll
        for (int p = 0; p < 4; p++) {
            int r = wid * 32 + p * 8;
            gld16(&ub[(size_t)tok_a[p] * DMODEL + k0 + scol], &As[r * 64]);
            gld16(&bbase[(size_t)(r + srow) * DMODEL + k0 + scol], &Bs[r * 64]);
        }
        __syncthreads();
#pragma unroll
        for (int ks = 0; ks < 2; ks++) {
            int kk = ks * 32 + lk4 * 8;
            s16x8 a[4], b[4];
#pragma unroll
            for (int i = 0; i < 4; i++)
                a[i] = *(const s16x8*)&As[(wm * 64 + i * 16 + lr) * 64 + kk];
#pragma unroll
            for (int j = 0; j < 4; j++)
                b[j] = *(const s16x8*)&Bs[(wn * 64 + j * 16 + lr) * 64 + kk];
#pragma unroll
            for (int i = 0; i < 4; i++)
#pragma unroll
                for (int j = 0; j < 4; j++)
                    acc[i][j] = __builtin_amdgcn_mfma_f32_16x16x32_bf16(
                        a[i], b[j], acc[i][j], 0, 0, 0);
        }
        __syncthreads();
    }

    const float* be = b17 + e * DMODEL;
    if (is_shared) {
#pragma unroll
        for (int i = 0; i < 4; i++) {
#pragma unroll
            for (int v = 0; v < 4; v++) {
                int row = row0 + wm * 64 + i * 16 + lk4 * 4 + v;
#pragma unroll
                for (int j = 0; j < 4; j++) {
                    int col = n0 + wn * 64 + j * 16 + lr;
                    size_t idx = (size_t)row * DMODEL + col;
                    out[idx] = u[idx] + 0.5f * (acc[i][j][v] + be[col]);
                }
            }
        }
    } else {
#pragma unroll
        for (int i = 0; i < 4; i++) {
#pragma unroll
            for (int v = 0; v < 4; v++) {
                int gi = row0 + wm * 64 + i * 16 + lk4 * 4 + v;
                if (gi < count) {
                    int id = idL[e * NTOK + gi];
                    float g = gateL[e * NTOK + gi];
                    float* yr = y + (size_t)id * DMODEL;
#pragma unroll
                    for (int j = 0; j < 4; j++) {
                        int col = n0 + wn * 64 + j * 16 + lr;
                        yr[col] = g * (acc[i][j][v] + be[col]);
                    }
                }
            }
        }
    }
}

// out[t] += y[2t] + y[2t+1]
__global__ void combine_kernel(const float* __restrict__ y, float* __restrict__ out) {
    int idx = blockIdx.x * 256 + threadIdx.x;
    size_t base = (size_t)idx * 4;
    int tk = idx >> 8;
    int d4 = idx & 255;
    f32x4 o  = *(const f32x4*)&out[base];
    f32x4 y0 = *(const f32x4*)&y[(size_t)(tk * 2) * DMODEL + d4 * 4];
    f32x4 y1 = *(const f32x4*)&y[(size_t)(tk * 2 + 1) * DMODEL + d4 * 4];
#pragma unroll
    for (int v = 0; v < 4; v++) o[v] += y0[v] + y1[v];
    *(f32x4*)&out[base] = o;
}

extern "C" void kernel_launch(void* const* d_in, const int* in_sizes, int n_in,
                              void* d_out, int out_size, void* d_ws, size_t ws_size,
                              hipStream_t stream) {
    const float* u    = (const float*)d_in[0];
    const float* cent = (const float*)d_in[1];
    const float* eb   = (const float*)d_in[2];
    const float* Wr   = (const float*)d_in[3];
    const float* br   = (const float*)d_in[4];
    const float* Ws   = (const float*)d_in[5];
    const float* bs   = (const float*)d_in[6];
    float* out = (float*)d_out;

    char* ws = (char*)d_ws;
    size_t off = 0;
    auto take = [&](size_t b) { size_t o = off; off += (b + 255) & ~(size_t)255; return o; };
    float* topk_g = (float*)(ws + take(NTOK * TOPK * 4));
    int*   topk_i = (int*)  (ws + take(NTOK * TOPK * 4));
    int*   cnt    = (int*)  (ws + take(64 * 4));
    int*   tokL   = (int*)  (ws + take((size_t)NEXP * NTOK * 4));
    float* gateL  = (float*)(ws + take((size_t)NEXP * NTOK * 4));
    int*   idL    = (int*)  (ws + take((size_t)NEXP * NTOK * 4));
    int*   desc   = (int*)  (ws + take(MAXT * 4));
    int*   numT   = (int*)  (ws + take(64));
    float* b17    = (float*)(ws + take((size_t)(NEXP + 1) * DMODEL * 4));
    unsigned short* ub  = (unsigned short*)(ws + take((size_t)NTOK * DMODEL * 2));
    unsigned short* w17 = (unsigned short*)(ws + take((size_t)(NEXP + 1) * DMODEL * DMODEL * 2));
    float* y = (float*)(ws + take((size_t)NTOK * TOPK * DMODEL * 4));

    routing_kernel<<<NTOK / 4, 256, 0, stream>>>(u, cent, eb, topk_g, topk_i, ub);
    build_all<<<1, 1024, 0, stream>>>(topk_g, topk_i, cnt, tokL, gateL, idL, desc, numT);
    conv_w<<<(NWR8 + NWS8 + NB8 + 255) / 256, 256, 0, stream>>>(Wr, br, Ws, bs, w17, b17);
    moe_gemm<<<dim3(DMODEL / 128, MAXT), 256, 0, stream>>>(
        ub, w17, b17, cnt, tokL, gateL, idL, desc, numT, u, out, y);
    combine_kernel<<<(NTOK * DMODEL / 4) / 256, 256, 0, stream>>>(y, out);
}

// Round 5
// 122.846 us; speedup vs baseline: 2.6917x; 1.0556x over previous
//
#include <hip/hip_runtime.h>

typedef unsigned short u16x8 __attribute__((ext_vector_type(8)));
typedef short          s16x8 __attribute__((ext_vector_type(8)));
typedef float          f32x4 __attribute__((ext_vector_type(4)));

#define NTOK   4096      // B*S
#define DMODEL 1024
#define NEXP   16
#define TOPK   2
#define BK     32
#define NK     (DMODEL / BK)   // 32 K-steps
#define MAXT   72        // 16 shared tiles + <=48 routed tiles (BM=256)

// RNE float->bf16
__device__ inline unsigned short f2bf(float f) {
    unsigned int x = __float_as_uint(f);
    x += 0x7fffu + ((x >> 16) & 1u);
    return (unsigned short)(x >> 16);
}

// async global->LDS, 16B/lane; LDS dest wave-uniform base, HW adds lane*16
__device__ inline void gld16(const void* g, void* l) {
    __builtin_amdgcn_global_load_lds(
        (const __attribute__((address_space(1))) void*)g,
        (__attribute__((address_space(3))) void*)l, 16, 0, 0);
}

// ------------- routing: fp64 scores, softmax, top-2; fused u->bf16 -------------
__global__ void routing_kernel(const float* __restrict__ u,
                               const float* __restrict__ cent,
                               const float* __restrict__ ebias,
                               float* __restrict__ topk_g,
                               int*   __restrict__ topk_i,
                               unsigned short* __restrict__ ub) {
    int wid  = threadIdx.x >> 6;
    int lane = threadIdx.x & 63;
    int t = blockIdx.x * 4 + wid;
    const float* urow = u + (size_t)t * DMODEL;

    double acc[NEXP];
#pragma unroll
    for (int e = 0; e < NEXP; e++) acc[e] = 0.0;

    for (int j = 0; j < DMODEL / 64; j++) {
        int d = j * 64 + lane;
        float uf = urow[d];
        ub[(size_t)t * DMODEL + d] = f2bf(uf);
        double uv = (double)uf;
#pragma unroll
        for (int e = 0; e < NEXP; e++)
            acc[e] += uv * (double)cent[e * DMODEL + d];
    }
#pragma unroll
    for (int e = 0; e < NEXP; e++) {
        for (int off = 32; off; off >>= 1)
            acc[e] += __shfl_xor(acc[e], off);
    }
    if (lane == 0) {
        double mx = -1e300;
#pragma unroll
        for (int e = 0; e < NEXP; e++) {
            acc[e] += (double)ebias[e];
            if (acc[e] > mx) mx = acc[e];
        }
        double ex[NEXP], den = 0.0;
#pragma unroll
        for (int e = 0; e < NEXP; e++) { ex[e] = exp(acc[e] - mx); den += ex[e]; }
        int i1 = -1, i2 = -1;
        double v1 = -1.0, v2 = -1.0;
        for (int e = 0; e < NEXP; e++) {
            double v = ex[e];
            if (v > v1)      { v2 = v1; i2 = i1; v1 = v; i1 = e; }
            else if (v > v2) { v2 = v;  i2 = e; }
        }
        topk_g[t * 2 + 0] = (float)(v1 / den);
        topk_g[t * 2 + 1] = (float)(v2 / den);
        topk_i[t * 2 + 0] = i1;
        topk_i[t * 2 + 1] = i2;
    }
}

// ------------- single-block: bucket token-expert pairs + tile descriptors -------------
__global__ void build_all(const float* __restrict__ topk_g,
                          const int*   __restrict__ topk_i,
                          int* __restrict__ cnt,
                          int* __restrict__ tokL,
                          float* __restrict__ gateL,
                          int* __restrict__ idL,
                          int* __restrict__ desc,
                          int* __restrict__ numT) {
    __shared__ int scnt[NEXP];
    int tid = threadIdx.x;
    if (tid < NEXP) scnt[tid] = 0;
    __syncthreads();
    for (int id = tid; id < NTOK * TOPK; id += 1024) {
        int e = topk_i[id];
        int pos = atomicAdd(&scnt[e], 1);
        tokL[e * NTOK + pos]  = id >> 1;
        gateL[e * NTOK + pos] = topk_g[id];
        idL[e * NTOK + pos]   = id;
    }
    __syncthreads();
    if (tid == 0) {
        int s = 0;
        for (int mt = 0; mt < NTOK / 256; mt++) desc[s++] = (NEXP << 16) | mt; // shared
        for (int e = 0; e < NEXP; e++) {
            cnt[e] = scnt[e];
            int nt = (scnt[e] + 255) >> 8;
            for (int m = 0; m < nt; m++) desc[s++] = (e << 16) | m;
        }
        numT[0] = s;
    }
}

// ------------- all weight/bias conversions in one kernel -------------
#define NWR8  (NEXP * DMODEL * DMODEL / 8)       // 2097152
#define NWS8  (DMODEL * DMODEL / 8)              // 131072
#define NB8   ((NEXP + 1) * DMODEL / 8)          // 2176
__global__ void conv_w(const float* __restrict__ Wr,
                       const float* __restrict__ br,
                       const float* __restrict__ Ws,
                       const float* __restrict__ bs,
                       unsigned short* __restrict__ w17,
                       float* __restrict__ b17) {
    int id = blockIdx.x * 256 + threadIdx.x;
    if (id < NWR8) {
        size_t base = (size_t)id * 8;
        u16x8 o;
#pragma unroll
        for (int i = 0; i < 8; i++) o[i] = f2bf(Wr[base + i]);
        *(u16x8*)&w17[base] = o;
    } else if (id < NWR8 + NWS8) {
        size_t base = (size_t)(id - NWR8) * 8;
        u16x8 o;
#pragma unroll
        for (int i = 0; i < 8; i++)
            o[i] = f2bf(Ws[base + i] + Ws[(size_t)DMODEL * DMODEL + base + i]);
        *(u16x8*)&w17[(size_t)NEXP * DMODEL * DMODEL + base] = o;
    } else if (id < NWR8 + NWS8 + NB8) {
        int base = (id - NWR8 - NWS8) * 8;
#pragma unroll
        for (int i = 0; i < 8; i++) {
            int idx = base + i;
            b17[idx] = idx < NEXP * DMODEL ? br[idx]
                                           : bs[idx - NEXP * DMODEL] + bs[idx - NEXP * DMODEL + DMODEL];
        }
    }
}

// ============ merged MoE GEMM: 256x256 tile, BK=32, 3-buffer counted-vmcnt pipeline ============
// 8 waves (2M x 4N), per-wave output 128x64 (acc[8][4]).
// Depth-2 prefetch: stage kt+2 while computing kt; vmcnt(4) + one barrier per K-step.
__global__ __launch_bounds__(512, 2)
void moe_gemm(const unsigned short* __restrict__ ub,   // [4096][1024] bf16
              const unsigned short* __restrict__ w17,  // [17][1024][1024] bf16 (B^T)
              const float* __restrict__ b17,           // [17][1024]
              const int*   __restrict__ cnt,
              const int*   __restrict__ tokL,
              const float* __restrict__ gateL,
              const int*   __restrict__ idL,
              const int*   __restrict__ desc,
              const int*   __restrict__ numT,
              const float* __restrict__ u,
              float* __restrict__ out,
              float* __restrict__ y) {                 // [8192][1024] f32
    if ((int)blockIdx.y >= numT[0]) return;
    int d = desc[blockIdx.y];
    int e = d >> 16;
    int row0 = (d & 0xffff) << 8;
    bool is_shared = (e == NEXP);
    int count = is_shared ? NTOK : cnt[e];

    __shared__ __align__(16) unsigned short As[3][256 * BK];
    __shared__ __align__(16) unsigned short Bs[3][256 * BK];

    int t = threadIdx.x;
    int lane = t & 63, wid = t >> 6;
    int n0 = blockIdx.x * 256;
    int wm = wid >> 2, wn = wid & 3;
    int lr = lane & 15, lk4 = lane >> 4;

    // staging geometry: one gld16 call covers 128 rows (wave wid covers rows wid*16..+16)
    int srow_w = wid * 16 + (lane >> 2);      // row within 128-row half
    int schunk = (lane & 3) * 8;              // element offset of this lane's 16B

    const int* tl = tokL + e * NTOK;
    int tokA[2];
#pragma unroll
    for (int p = 0; p < 2; p++) {
        int gi = row0 + p * 128 + srow_w;
        if (is_shared) tokA[p] = gi;
        else           tokA[p] = tl[gi < count ? gi : count - 1];
    }
    const unsigned short* bb = w17 + (size_t)e * DMODEL * DMODEL + (size_t)n0 * DMODEL;

#define STAGE(buf, kt) do {                                                       \
    int _k0 = (kt) * BK;                                                          \
    gld16(&ub[(size_t)tokA[0] * DMODEL + _k0 + schunk], &As[buf][(wid * 16) * BK]);          \
    gld16(&ub[(size_t)tokA[1] * DMODEL + _k0 + schunk], &As[buf][(128 + wid * 16) * BK]);    \
    gld16(&bb[(size_t)(srow_w) * DMODEL + _k0 + schunk], &Bs[buf][(wid * 16) * BK]);         \
    gld16(&bb[(size_t)(128 + srow_w) * DMODEL + _k0 + schunk], &Bs[buf][(128 + wid * 16) * BK]); \
} while (0)

    f32x4 acc[8][4];
#pragma unroll
    for (int i = 0; i < 8; i++)
#pragma unroll
        for (int j = 0; j < 4; j++)
#pragma unroll
            for (int v = 0; v < 4; v++) acc[i][j][v] = 0.0f;

    // prologue: fill buffers 0,1 (K-tiles 0,1); drain tile 0's 4 loads
    STAGE(0, 0);
    STAGE(1, 1);
    asm volatile("s_waitcnt vmcnt(4)" ::: "memory");
    __builtin_amdgcn_s_barrier();

    int cb = 0;   // compute buffer for kt
    for (int kt = 0; kt < NK; kt++) {
        int sb = (cb == 0) ? 2 : cb - 1;         // (cb+2)%3
        if (kt + 2 < NK) STAGE(sb, kt + 2);

        __builtin_amdgcn_s_setprio(1);
        s16x8 b[4];
#pragma unroll
        for (int j = 0; j < 4; j++)
            b[j] = *(const s16x8*)&Bs[cb][(wn * 64 + j * 16 + lr) * BK + lk4 * 8];
#pragma unroll
        for (int i = 0; i < 8; i++) {
            s16x8 a = *(const s16x8*)&As[cb][(wm * 128 + i * 16 + lr) * BK + lk4 * 8];
#pragma unroll
            for (int j = 0; j < 4; j++)
                acc[i][j] = __builtin_amdgcn_mfma_f32_16x16x32_bf16(a, b[j], acc[i][j], 0, 0, 0);
        }
        __builtin_amdgcn_s_setprio(0);

        // steady state: leave kt+2's 4 loads in flight; drain kt+1's
        if (kt + 2 < NK) asm volatile("s_waitcnt vmcnt(4)" ::: "memory");
        else             asm volatile("s_waitcnt vmcnt(0)" ::: "memory");
        __builtin_amdgcn_s_barrier();
        cb = (cb == 2) ? 0 : cb + 1;
    }
#undef STAGE

    const float* be = b17 + e * DMODEL;
    if (is_shared) {
#pragma unroll
        for (int i = 0; i < 8; i++) {
#pragma unroll
            for (int v = 0; v < 4; v++) {
                int row = row0 + wm * 128 + i * 16 + lk4 * 4 + v;
#pragma unroll
                for (int j = 0; j < 4; j++) {
                    int col = n0 + wn * 64 + j * 16 + lr;
                    size_t idx = (size_t)row * DMODEL + col;
                    out[idx] = u[idx] + 0.5f * (acc[i][j][v] + be[col]);
                }
            }
        }
    } else {
#pragma unroll
        for (int i = 0; i < 8; i++) {
#pragma unroll
            for (int v = 0; v < 4; v++) {
                int gi = row0 + wm * 128 + i * 16 + lk4 * 4 + v;
                if (gi < count) {
                    int id = idL[e * NTOK + gi];
                    float g = gateL[e * NTOK + gi];
                    float* yr = y + (size_t)id * DMODEL;
#pragma unroll
                    for (int j = 0; j < 4; j++) {
                        int col = n0 + wn * 64 + j * 16 + lr;
                        yr[col] = g * (acc[i][j][v] + be[col]);
                    }
                }
            }
        }
    }
}

// out[t] += y[2t] + y[2t+1]
__global__ void combine_kernel(const float* __restrict__ y, float* __restrict__ out) {
    int idx = blockIdx.x * 256 + threadIdx.x;
    size_t base = (size_t)idx * 4;
    int tk = idx >> 8;
    int d4 = idx & 255;
    f32x4 o  = *(const f32x4*)&out[base];
    f32x4 y0 = *(const f32x4*)&y[(size_t)(tk * 2) * DMODEL + d4 * 4];
    f32x4 y1 = *(const f32x4*)&y[(size_t)(tk * 2 + 1) * DMODEL + d4 * 4];
#pragma unroll
    for (int v = 0; v < 4; v++) o[v] += y0[v] + y1[v];
    *(f32x4*)&out[base] = o;
}

extern "C" void kernel_launch(void* const* d_in, const int* in_sizes, int n_in,
                              void* d_out, int out_size, void* d_ws, size_t ws_size,
                              hipStream_t stream) {
    const float* u    = (const float*)d_in[0];
    const float* cent = (const float*)d_in[1];
    const float* eb   = (const float*)d_in[2];
    const float* Wr   = (const float*)d_in[3];
    const float* br   = (const float*)d_in[4];
    const float* Ws   = (const float*)d_in[5];
    const float* bs   = (const float*)d_in[6];
    float* out = (float*)d_out;

    char* ws = (char*)d_ws;
    size_t off = 0;
    auto take = [&](size_t b) { size_t o = off; off += (b + 255) & ~(size_t)255; return o; };
    float* topk_g = (float*)(ws + take(NTOK * TOPK * 4));
    int*   topk_i = (int*)  (ws + take(NTOK * TOPK * 4));
    int*   cnt    = (int*)  (ws + take(64 * 4));
    int*   tokL   = (int*)  (ws + take((size_t)NEXP * NTOK * 4));
    float* gateL  = (float*)(ws + take((size_t)NEXP * NTOK * 4));
    int*   idL    = (int*)  (ws + take((size_t)NEXP * NTOK * 4));
    int*   desc   = (int*)  (ws + take(MAXT * 4));
    int*   numT   = (int*)  (ws + take(64));
    float* b17    = (float*)(ws + take((size_t)(NEXP + 1) * DMODEL * 4));
    unsigned short* ub  = (unsigned short*)(ws + take((size_t)NTOK * DMODEL * 2));
    unsigned short* w17 = (unsigned short*)(ws + take((size_t)(NEXP + 1) * DMODEL * DMODEL * 2));
    float* y = (float*)(ws + take((size_t)NTOK * TOPK * DMODEL * 4));

    routing_kernel<<<NTOK / 4, 256, 0, stream>>>(u, cent, eb, topk_g, topk_i, ub);
    build_all<<<1, 1024, 0, stream>>>(topk_g, topk_i, cnt, tokL, gateL, idL, desc, numT);
    conv_w<<<(NWR8 + NWS8 + NB8 + 255) / 256, 256, 0, stream>>>(Wr, br, Ws, bs, w17, b17);
    moe_gemm<<<dim3(DMODEL / 256, MAXT), 512, 0, stream>>>(
        ub, w17, b17, cnt, tokL, gateL, idL, desc, numT, u, out, y);
    combine_kernel<<<(NTOK * DMODEL / 4) / 256, 256, 0, stream>>>(y, out);
}

// Round 6
// 119.484 us; speedup vs baseline: 2.7675x; 1.0281x over previous
//
#include <hip/hip_runtime.h>

typedef unsigned short u16x8 __attribute__((ext_vector_type(8)));
typedef short          s16x8 __attribute__((ext_vector_type(8)));
typedef float          f32x4 __attribute__((ext_vector_type(4)));

#define NTOK   4096      // B*S
#define DMODEL 1024
#define NEXP   16
#define TOPK   2
#define BK     32
#define NK     (DMODEL / BK)   // 32 K-steps
#define MAXT   128       // 32 shared tiles + <=80 routed tiles (BM=128)

// RNE float->bf16
__device__ inline unsigned short f2bf(float f) {
    unsigned int x = __float_as_uint(f);
    x += 0x7fffu + ((x >> 16) & 1u);
    return (unsigned short)(x >> 16);
}

// async global->LDS, 16B/lane; LDS dest wave-uniform base, HW adds lane*16
__device__ inline void gld16(const void* g, void* l) {
    __builtin_amdgcn_global_load_lds(
        (const __attribute__((address_space(1))) void*)g,
        (__attribute__((address_space(3))) void*)l, 16, 0, 0);
}

// ------------- routing: fp64 scores, softmax, top-2; fused u->bf16 -------------
__global__ void routing_kernel(const float* __restrict__ u,
                               const float* __restrict__ cent,
                               const float* __restrict__ ebias,
                               float* __restrict__ topk_g,
                               int*   __restrict__ topk_i,
                               unsigned short* __restrict__ ub) {
    int wid  = threadIdx.x >> 6;
    int lane = threadIdx.x & 63;
    int t = blockIdx.x * 4 + wid;
    const float* urow = u + (size_t)t * DMODEL;

    double acc[NEXP];
#pragma unroll
    for (int e = 0; e < NEXP; e++) acc[e] = 0.0;

    for (int j = 0; j < DMODEL / 64; j++) {
        int d = j * 64 + lane;
        float uf = urow[d];
        ub[(size_t)t * DMODEL + d] = f2bf(uf);
        double uv = (double)uf;
#pragma unroll
        for (int e = 0; e < NEXP; e++)
            acc[e] += uv * (double)cent[e * DMODEL + d];
    }
#pragma unroll
    for (int e = 0; e < NEXP; e++) {
        for (int off = 32; off; off >>= 1)
            acc[e] += __shfl_xor(acc[e], off);
    }
    if (lane == 0) {
        double mx = -1e300;
#pragma unroll
        for (int e = 0; e < NEXP; e++) {
            acc[e] += (double)ebias[e];
            if (acc[e] > mx) mx = acc[e];
        }
        double ex[NEXP], den = 0.0;
#pragma unroll
        for (int e = 0; e < NEXP; e++) { ex[e] = exp(acc[e] - mx); den += ex[e]; }
        int i1 = -1, i2 = -1;
        double v1 = -1.0, v2 = -1.0;
        for (int e = 0; e < NEXP; e++) {
            double v = ex[e];
            if (v > v1)      { v2 = v1; i2 = i1; v1 = v; i1 = e; }
            else if (v > v2) { v2 = v;  i2 = e; }
        }
        topk_g[t * 2 + 0] = (float)(v1 / den);
        topk_g[t * 2 + 1] = (float)(v2 / den);
        topk_i[t * 2 + 0] = i1;
        topk_i[t * 2 + 1] = i2;
    }
}

// ------------- single-block: bucket token-expert pairs + tile descriptors -------------
__global__ void build_all(const float* __restrict__ topk_g,
                          const int*   __restrict__ topk_i,
                          int* __restrict__ cnt,
                          int* __restrict__ tokL,
                          float* __restrict__ gateL,
                          int* __restrict__ idL,
                          int* __restrict__ desc,
                          int* __restrict__ numT) {
    __shared__ int scnt[NEXP];
    int tid = threadIdx.x;
    if (tid < NEXP) scnt[tid] = 0;
    __syncthreads();
    for (int id = tid; id < NTOK * TOPK; id += 1024) {
        int e = topk_i[id];
        int pos = atomicAdd(&scnt[e], 1);
        tokL[e * NTOK + pos]  = id >> 1;
        gateL[e * NTOK + pos] = topk_g[id];
        idL[e * NTOK + pos]   = id;
    }
    __syncthreads();
    if (tid == 0) {
        int s = 0;
        for (int mt = 0; mt < NTOK / 128; mt++) desc[s++] = (NEXP << 16) | mt; // shared
        for (int e = 0; e < NEXP; e++) {
            cnt[e] = scnt[e];
            int nt = (scnt[e] + 127) >> 7;
            for (int m = 0; m < nt; m++) desc[s++] = (e << 16) | m;
        }
        numT[0] = s;
    }
}

// ------------- all weight/bias conversions in one kernel -------------
#define NWR8  (NEXP * DMODEL * DMODEL / 8)       // 2097152
#define NWS8  (DMODEL * DMODEL / 8)              // 131072
#define NB8   ((NEXP + 1) * DMODEL / 8)          // 2176
__global__ void conv_w(const float* __restrict__ Wr,
                       const float* __restrict__ br,
                       const float* __restrict__ Ws,
                       const float* __restrict__ bs,
                       unsigned short* __restrict__ w17,
                       float* __restrict__ b17) {
    int id = blockIdx.x * 256 + threadIdx.x;
    if (id < NWR8) {
        size_t base = (size_t)id * 8;
        u16x8 o;
#pragma unroll
        for (int i = 0; i < 8; i++) o[i] = f2bf(Wr[base + i]);
        *(u16x8*)&w17[base] = o;
    } else if (id < NWR8 + NWS8) {
        size_t base = (size_t)(id - NWR8) * 8;
        u16x8 o;
#pragma unroll
        for (int i = 0; i < 8; i++)
            o[i] = f2bf(Ws[base + i] + Ws[(size_t)DMODEL * DMODEL + base + i]);
        *(u16x8*)&w17[(size_t)NEXP * DMODEL * DMODEL + base] = o;
    } else if (id < NWR8 + NWS8 + NB8) {
        int base = (id - NWR8 - NWS8) * 8;
#pragma unroll
        for (int i = 0; i < 8; i++) {
            int idx = base + i;
            b17[idx] = idx < NEXP * DMODEL ? br[idx]
                                           : bs[idx - NEXP * DMODEL] + bs[idx - NEXP * DMODEL + DMODEL];
        }
    }
}

// ============ merged MoE GEMM: 128x128 tile, BK=32, dbuf counted-vmcnt, XOR swizzle ============
// 4 waves (2x2), per-wave 64x64 out (acc[4][4]), 16 MFMA + 8 ds_read_b128 per K-step.
// LDS 32KB (2 buf x (A+B) x 128x32 bf16) -> 4 blocks/CU with launch_bounds(256,4).
// Swizzle: logical (row, chunk c) stored at phys chunk c ^ ((row>>1)&3) (16B units).
//   - global_load_lds dest stays LINEAR; SOURCE chunk per lane = (l&3)^((l>>3)&3)
//   - ds_read applies the same XOR -> quarter-wave reads spread to 8 slots (2-way, free)
__global__ __launch_bounds__(256, 4)
void moe_gemm(const unsigned short* __restrict__ ub,   // [4096][1024] bf16
              const unsigned short* __restrict__ w17,  // [17][1024][1024] bf16 (B^T)
              const float* __restrict__ b17,           // [17][1024]
              const int*   __restrict__ cnt,
              const int*   __restrict__ tokL,
              const float* __restrict__ gateL,
              const int*   __restrict__ idL,
              const int*   __restrict__ desc,
              const int*   __restrict__ numT,
              const float* __restrict__ u,
              float* __restrict__ out,
              float* __restrict__ y) {                 // [8192][1024] f32
    int bid = blockIdx.x;
    int tile = bid >> 3;              // n fastest -> XCD = bid%8 = n-panel
    int n0 = (bid & 7) * 128;
    if (tile >= numT[0]) return;
    int d = desc[tile];
    int e = d >> 16;
    int row0 = (d & 0xffff) << 7;
    bool is_shared = (e == NEXP);
    int count = is_shared ? NTOK : cnt[e];

    __shared__ __align__(16) unsigned short As[2][128 * BK];
    __shared__ __align__(16) unsigned short Bs[2][128 * BK];

    int t = threadIdx.x;
    int lane = t & 63, wid = t >> 6;
    int wm = wid >> 1, wn = wid & 1;
    int lr = lane & 15, lk4 = lane >> 4;
    int rchunk = (lk4 ^ ((lr >> 1) & 3)) * 8;        // swizzled read chunk (elems)

    // staging: wave w covers rows [w*32, w*32+32) of A and B, 2 gld16 each (16 rows/call)
    int srow = lane >> 2;                            // 0..15 row within 16-row group
    int scs  = ((lane & 3) ^ ((lane >> 3) & 3)) * 8; // inverse-swizzled source chunk (elems)

    const int* tl = tokL + e * NTOK;
    const unsigned short* asrc[2];
    const unsigned short* bsrc[2];
    const unsigned short* bb = w17 + (size_t)e * DMODEL * DMODEL + (size_t)n0 * DMODEL;
#pragma unroll
    for (int p = 0; p < 2; p++) {
        int gi = row0 + wid * 32 + p * 16 + srow;
        int tok = is_shared ? gi : tl[gi < count ? gi : count - 1];
        asrc[p] = ub + (size_t)tok * DMODEL + scs;
        bsrc[p] = bb + (size_t)(wid * 32 + p * 16 + srow) * DMODEL + scs;
    }

#define STAGE(buf, kt) do {                                                     \
    int _k0 = (kt) * BK;                                                        \
    _Pragma("unroll")                                                           \
    for (int p = 0; p < 2; p++) {                                               \
        int r = wid * 32 + p * 16;                                              \
        gld16(asrc[p] + _k0, &As[buf][r * BK]);                                 \
        gld16(bsrc[p] + _k0, &Bs[buf][r * BK]);                                 \
    } } while (0)

    f32x4 acc[4][4];
#pragma unroll
    for (int i = 0; i < 4; i++)
#pragma unroll
        for (int j = 0; j < 4; j++)
#pragma unroll
            for (int v = 0; v < 4; v++) acc[i][j][v] = 0.0f;

    STAGE(0, 0);
    int cur = 0;
    for (int kt = 0; kt < NK; kt++) {
        if (kt + 1 < NK) {
            STAGE(cur ^ 1, kt + 1);                        // 8 outstanding
            asm volatile("s_waitcnt vmcnt(4)" ::: "memory"); // kt's 4 landed
        } else {
            asm volatile("s_waitcnt vmcnt(0)" ::: "memory");
        }
        __builtin_amdgcn_s_barrier();

        __builtin_amdgcn_s_setprio(1);
        s16x8 b[4];
#pragma unroll
        for (int j = 0; j < 4; j++)
            b[j] = *(const s16x8*)&Bs[cur][(wn * 64 + j * 16 + lr) * BK + rchunk];
#pragma unroll
        for (int i = 0; i < 4; i++) {
            s16x8 a = *(const s16x8*)&As[cur][(wm * 64 + i * 16 + lr) * BK + rchunk];
#pragma unroll
            for (int j = 0; j < 4; j++)
                acc[i][j] = __builtin_amdgcn_mfma_f32_16x16x32_bf16(a, b[j], acc[i][j], 0, 0, 0);
        }
        __builtin_amdgcn_s_setprio(0);

        asm volatile("" ::: "memory");               // keep ds_reads above barrier
        __builtin_amdgcn_s_barrier();
        cur ^= 1;
    }
#undef STAGE

    const float* be = b17 + e * DMODEL;
    if (is_shared) {
#pragma unroll
        for (int i = 0; i < 4; i++) {
#pragma unroll
            for (int v = 0; v < 4; v++) {
                int row = row0 + wm * 64 + i * 16 + lk4 * 4 + v;
#pragma unroll
                for (int j = 0; j < 4; j++) {
                    int col = n0 + wn * 64 + j * 16 + lr;
                    size_t idx = (size_t)row * DMODEL + col;
                    out[idx] = u[idx] + 0.5f * (acc[i][j][v] + be[col]);
                }
            }
        }
    } else {
#pragma unroll
        for (int i = 0; i < 4; i++) {
#pragma unroll
            for (int v = 0; v < 4; v++) {
                int gi = row0 + wm * 64 + i * 16 + lk4 * 4 + v;
                if (gi < count) {
                    int id = idL[e * NTOK + gi];
                    float g = gateL[e * NTOK + gi];
                    float* yr = y + (size_t)id * DMODEL;
#pragma unroll
                    for (int j = 0; j < 4; j++) {
                        int col = n0 + wn * 64 + j * 16 + lr;
                        yr[col] = g * (acc[i][j][v] + be[col]);
                    }
                }
            }
        }
    }
}

// out[t] += y[2t] + y[2t+1]
__global__ void combine_kernel(const float* __restrict__ y, float* __restrict__ out) {
    int idx = blockIdx.x * 256 + threadIdx.x;
    size_t base = (size_t)idx * 4;
    int tk = idx >> 8;
    int d4 = idx & 255;
    f32x4 o  = *(const f32x4*)&out[base];
    f32x4 y0 = *(const f32x4*)&y[(size_t)(tk * 2) * DMODEL + d4 * 4];
    f32x4 y1 = *(const f32x4*)&y[(size_t)(tk * 2 + 1) * DMODEL + d4 * 4];
#pragma unroll
    for (int v = 0; v < 4; v++) o[v] += y0[v] + y1[v];
    *(f32x4*)&out[base] = o;
}

extern "C" void kernel_launch(void* const* d_in, const int* in_sizes, int n_in,
                              void* d_out, int out_size, void* d_ws, size_t ws_size,
                              hipStream_t stream) {
    const float* u    = (const float*)d_in[0];
    const float* cent = (const float*)d_in[1];
    const float* eb   = (const float*)d_in[2];
    const float* Wr   = (const float*)d_in[3];
    const float* br   = (const float*)d_in[4];
    const float* Ws   = (const float*)d_in[5];
    const float* bs   = (const float*)d_in[6];
    float* out = (float*)d_out;

    char* ws = (char*)d_ws;
    size_t off = 0;
    auto take = [&](size_t b) { size_t o = off; off += (b + 255) & ~(size_t)255; return o; };
    float* topk_g = (float*)(ws + take(NTOK * TOPK * 4));
    int*   topk_i = (int*)  (ws + take(NTOK * TOPK * 4));
    int*   cnt    = (int*)  (ws + take(64 * 4));
    int*   tokL   = (int*)  (ws + take((size_t)NEXP * NTOK * 4));
    float* gateL  = (float*)(ws + take((size_t)NEXP * NTOK * 4));
    int*   idL    = (int*)  (ws + take((size_t)NEXP * NTOK * 4));
    int*   desc   = (int*)  (ws + take(MAXT * 4));
    int*   numT   = (int*)  (ws + take(64));
    float* b17    = (float*)(ws + take((size_t)(NEXP + 1) * DMODEL * 4));
    unsigned short* ub  = (unsigned short*)(ws + take((size_t)NTOK * DMODEL * 2));
    unsigned short* w17 = (unsigned short*)(ws + take((size_t)(NEXP + 1) * DMODEL * DMODEL * 2));
    float* y = (float*)(ws + take((size_t)NTOK * TOPK * DMODEL * 4));

    routing_kernel<<<NTOK / 4, 256, 0, stream>>>(u, cent, eb, topk_g, topk_i, ub);
    build_all<<<1, 1024, 0, stream>>>(topk_g, topk_i, cnt, tokL, gateL, idL, desc, numT);
    conv_w<<<(NWR8 + NWS8 + NB8 + 255) / 256, 256, 0, stream>>>(Wr, br, Ws, bs, w17, b17);
    moe_gemm<<<8 * MAXT, 256, 0, stream>>>(
        ub, w17, b17, cnt, tokL, gateL, idL, desc, numT, u, out, y);
    combine_kernel<<<(NTOK * DMODEL / 4) / 256, 256, 0, stream>>>(y, out);
}